// Round 4
// baseline (148.247 us; speedup 1.0000x reference)
//
#include <hip/hip_runtime.h>
#include <hip/hip_bf16.h>

#define M_DIM 4096
#define N_DIM 4096
#define K_DIM 4096

typedef __attribute__((ext_vector_type(8))) __bf16 bf16x8;
typedef __attribute__((ext_vector_type(8))) short short8;
typedef __attribute__((ext_vector_type(8))) unsigned short ushort8;
typedef __attribute__((ext_vector_type(4))) float f32x4;

// async global->LDS, 16B/lane (m104: dest = wave-uniform base + lane*16)
__device__ __forceinline__ void gload_lds16(const void* g, void* l) {
    __builtin_amdgcn_global_load_lds(
        (const __attribute__((address_space(1))) void*)g,
        (__attribute__((address_space(3))) void*)l,
        16, 0, 0);
}

__device__ __forceinline__ bf16x8 ld8(const unsigned short* p) {
    short8 r = *reinterpret_cast<const short8*>(p);
    return __builtin_bit_cast(bf16x8, r);
}

// ---------------------------------------------------------------------------
// fused fp32->bf16 conversion: x (pruned) and w (unpruned) in ONE launch
// ---------------------------------------------------------------------------
__global__ void prune_cvt2(const float* __restrict__ x,
                           const float* __restrict__ w,
                           unsigned short* __restrict__ xb,
                           unsigned short* __restrict__ wb,
                           const float* __restrict__ thrp, int n8) {
    const float thr = thrp[0];
    const int stride = gridDim.x * blockDim.x;
    const int total = 2 * n8;
    for (int idx = blockIdx.x * blockDim.x + threadIdx.x; idx < total; idx += stride) {
        const bool isx = idx < n8;
        const int j = isx ? idx : idx - n8;
        const float* src = isx ? x : w;
        unsigned short* dst = isx ? xb : wb;
        const float te = isx ? thr : -1.0f;   // |v| > -1 always true -> keep all
        const float4* p = reinterpret_cast<const float4*>(src) + 2 * (size_t)j;
        float4 v0 = p[0];
        float4 v1 = p[1];
        float v[8] = {v0.x, v0.y, v0.z, v0.w, v1.x, v1.y, v1.z, v1.w};
        ushort8 o;
#pragma unroll
        for (int e = 0; e < 8; ++e) {
            float f = v[e];
            f = (fabsf(f) > te) ? f : 0.0f;   // prune in fp32 (exact predicate)
            __hip_bfloat16 hh = __float2bfloat16(f);
            o[e] = *reinterpret_cast<unsigned short*>(&hh);
        }
        *reinterpret_cast<ushort8*>(dst + 8 * (size_t)j) = o;
    }
}

// ---------------------------------------------------------------------------
// C = A * B^T, 256x256 tile, BK=64, 8 waves, kk-major 4-phase pipeline.
//
// Phases: {m0-3/kk0, m4-7/kk0, m0-3/kk1, m4-7/kk1} -> every phase:
//   6 ds_read_b128 (4 A-frag prefetch + 2 B-frag prefetch), 16 MFMA,
//   0 or 4 global_load_lds.  A staged 1 tile ahead (ph1), B staged 2 tiles
//   ahead (ph3).  Waits: -/vmcnt(4)/vmcnt(2)/vmcnt(4) — min slack 2.5 phases,
//   never drains in the loop.
//
// LDS per buffer: A[256][64], B[256][64], slot-swizzled:
//   element(row, logical col c) at row*64 + 8*((c>>3) ^ (row&7)) + (c&7)
// ---------------------------------------------------------------------------
__global__ __launch_bounds__(512, 2) void gemm_8phase(
        const unsigned short* __restrict__ A,
        const unsigned short* __restrict__ B,
        float* __restrict__ C) {
    __shared__ __align__(16) unsigned short lds[65536];  // 128 KB

    const int tid  = threadIdx.x;
    const int lane = tid & 63;
    const int wid  = tid >> 6;
    const int wr   = wid >> 2;   // 0..1 : 128-row strip
    const int wc   = wid & 3;    // 0..3 : 64-col strip

    // XCD-aware bijective swizzle (256 blocks / 8 XCDs)
    const int bid = blockIdx.x;
    const int swz = (bid & 7) * 32 + (bid >> 3);
    const int bm = (swz >> 4) * 256;
    const int bn = (swz & 15) * 256;

    // staging: A-half ah staged by threads [ah*256, +256); load j = rows [32j,+32)
    const int g  = tid & 255;
    const int ah = tid >> 8;
    const int arow = bm + ah * 128 + (g >> 3);
    const int acol = 8 * ((g & 7) ^ ((g >> 3) & 7));      // pre-swizzled source col
    const unsigned short* Asrc = A + (size_t)arow * K_DIM + acol;
    const int AdstE = ah * 8192 + g * 8;

    const int h = lane + 64 * wr;
    const int brow = bn + wc * 64 + (h >> 3);
    const int bcol = 8 * ((h & 7) ^ ((h >> 3) & 7));
    const unsigned short* Bsrc = B + (size_t)brow * K_DIM + bcol;
    const int BdstE = wc * 4096 + h * 8;

#define SA(dstb, j, kg) gload_lds16(Asrc + (size_t)(32*(j))*K_DIM + (kg), (dstb) + AdstE + 2048*(j))
#define SB(dstb, j, kg) gload_lds16(Bsrc + (size_t)(16*(j))*K_DIM + (kg), (dstb) + BdstE + 1024*(j))

    // fragment read offsets (row&7 == fr&7 -> swizzle slot is thread-constant)
    const int fr  = lane & 15;
    const int kq4 = lane >> 4;
    const int rowOffA = (wr * 128 + fr) * 64;
    const int rowOffB = (wc * 64 + fr) * 64;
    const int sk0 = 8 * ((kq4    ) ^ (fr & 7));
    const int sk1 = 8 * ((kq4 + 4) ^ (fr & 7));

    f32x4 acc[8][4] = {};

    // frag register sets: two A-quads, two B-quads, alternate per phase
    bf16x8 aA0, aA1, aA2, aA3;   // setA
    bf16x8 aB0, aB1, aB2, aB3;   // setB
    bf16x8 b00, b01, b02, b03;   // Bs0
    bf16x8 b10, b11, b12, b13;   // Bs1

#define PH_MFMA(q, S0, S1, S2, S3, T0, T1, T2, T3)                              \
    {                                                                           \
        __builtin_amdgcn_s_setprio(1);                                          \
        const bf16x8 Aq_[4] = {S0, S1, S2, S3};                                 \
        const bf16x8 Bq_[4] = {T0, T1, T2, T3};                                 \
        _Pragma("unroll")                                                       \
        for (int i_ = 0; i_ < 4; ++i_)                                          \
            _Pragma("unroll")                                                   \
            for (int n_ = 0; n_ < 4; ++n_)                                      \
                acc[4*(q)+i_][n_] = __builtin_amdgcn_mfma_f32_16x16x32_bf16(    \
                    Aq_[i_], Bq_[n_], acc[4*(q)+i_][n_], 0, 0, 0);              \
        __builtin_amdgcn_s_setprio(0);                                          \
    }

    // ---- prologue: stage B(0),A(0) -> buf0, B(1) -> buf1 (B runs 2 ahead)
    SB(lds + 32768, 0, 0); SB(lds + 32768, 1, 0); SB(lds + 32768, 2, 0); SB(lds + 32768, 3, 0);
    SA(lds,         0, 0); SA(lds,         1, 0); SA(lds,         2, 0); SA(lds,         3, 0);
    SB(lds + 49152, 0, 64); SB(lds + 49152, 1, 64); SB(lds + 49152, 2, 64); SB(lds + 49152, 3, 64);
    asm volatile("s_waitcnt vmcnt(4)" ::: "memory");   // land B(0)+A(0); B(1) flying
    asm volatile("s_barrier" ::: "memory");

    // pre-read setA = A(0, m0-3, kk0), Bs0 = B(0) kk0
    aA0 = ld8(lds + rowOffA + 0 * 1024 + sk0);
    aA1 = ld8(lds + rowOffA + 1 * 1024 + sk0);
    aA2 = ld8(lds + rowOffA + 2 * 1024 + sk0);
    aA3 = ld8(lds + rowOffA + 3 * 1024 + sk0);
    b00 = ld8(lds + 32768 + rowOffB + 0 * 1024 + sk0);
    b01 = ld8(lds + 32768 + rowOffB + 1 * 1024 + sk0);
    b02 = ld8(lds + 32768 + rowOffB + 2 * 1024 + sk0);
    b03 = ld8(lds + 32768 + rowOffB + 3 * 1024 + sk0);

    for (int t = 0; t < 64; ++t) {
        const int cur = t & 1, nxt = cur ^ 1;
        const unsigned short* Ab   = lds + cur * 16384;           // A(t)
        const unsigned short* AbNr = lds + nxt * 16384;           // A(t+1) read
        unsigned short*       AbN  = lds + nxt * 16384;           // A(t+1) dest
        const unsigned short* Bb   = lds + 32768 + cur * 16384;   // B(t)
        const unsigned short* BbNr = lds + 32768 + nxt * 16384;   // B(t+1) read
        unsigned short*       BbC  = lds + 32768 + cur * 16384;   // B(t+2) dest
        const int kna = (t < 63 ? t + 1 : 63) * 64;   // clamp: tail stages are dead
        const int knb = (t < 62 ? t + 2 : 63) * 64;

        // ---- ph0: MFMA (m0-3,kk0) [setA,Bs0]; prefetch setB<-A(4-7,kk0), Bs1<-B(t)kk1 n0,1
        aB0 = ld8(Ab + rowOffA + 4 * 1024 + sk0);
        aB1 = ld8(Ab + rowOffA + 5 * 1024 + sk0);
        aB2 = ld8(Ab + rowOffA + 6 * 1024 + sk0);
        aB3 = ld8(Ab + rowOffA + 7 * 1024 + sk0);
        b10 = ld8(Bb + rowOffB + 0 * 1024 + sk1);
        b11 = ld8(Bb + rowOffB + 1 * 1024 + sk1);
        PH_MFMA(0, aA0, aA1, aA2, aA3, b00, b01, b02, b03);
        asm volatile("s_barrier" ::: "memory");

        // ---- ph1: MFMA (m4-7,kk0) [setB,Bs0]; prefetch setA<-A(0-3,kk1), Bs1 n2,3; stage A(t+1)
        aA0 = ld8(Ab + rowOffA + 0 * 1024 + sk1);
        aA1 = ld8(Ab + rowOffA + 1 * 1024 + sk1);
        aA2 = ld8(Ab + rowOffA + 2 * 1024 + sk1);
        aA3 = ld8(Ab + rowOffA + 3 * 1024 + sk1);
        b12 = ld8(Bb + rowOffB + 2 * 1024 + sk1);
        b13 = ld8(Bb + rowOffB + 3 * 1024 + sk1);
        SA(AbN, 0, kna); SA(AbN, 1, kna); SA(AbN, 2, kna); SA(AbN, 3, kna);
        PH_MFMA(1, aB0, aB1, aB2, aB3, b00, b01, b02, b03);
        asm volatile("s_waitcnt vmcnt(4)" ::: "memory");  // land B(t+1)x4; A(t+1)x4 flying
        asm volatile("s_barrier" ::: "memory");

        // ---- ph2: MFMA (m0-3,kk1) [setA,Bs1]; prefetch setB<-A(4-7,kk1), Bs0<-B(t+1)kk0 n0,1
        aB0 = ld8(Ab + rowOffA + 4 * 1024 + sk1);
        aB1 = ld8(Ab + rowOffA + 5 * 1024 + sk1);
        aB2 = ld8(Ab + rowOffA + 6 * 1024 + sk1);
        aB3 = ld8(Ab + rowOffA + 7 * 1024 + sk1);
        b00 = ld8(BbNr + rowOffB + 0 * 1024 + sk0);
        b01 = ld8(BbNr + rowOffB + 1 * 1024 + sk0);
        PH_MFMA(0, aA0, aA1, aA2, aA3, b10, b11, b12, b13);
        asm volatile("s_waitcnt vmcnt(2)" ::: "memory");  // land A(t+1) loads 0,1
        asm volatile("s_barrier" ::: "memory");

        // ---- ph3: MFMA (m4-7,kk1) [setB,Bs1]; prefetch setA<-A(t+1)(0-3,kk0), Bs0 n2,3; stage B(t+2)
        aA0 = ld8(AbNr + rowOffA + 0 * 1024 + sk0);
        aA1 = ld8(AbNr + rowOffA + 1 * 1024 + sk0);
        aA2 = ld8(AbNr + rowOffA + 2 * 1024 + sk0);
        aA3 = ld8(AbNr + rowOffA + 3 * 1024 + sk0);
        b02 = ld8(BbNr + rowOffB + 2 * 1024 + sk0);
        b03 = ld8(BbNr + rowOffB + 3 * 1024 + sk0);
        SB(BbC, 0, knb); SB(BbC, 1, knb); SB(BbC, 2, knb); SB(BbC, 3, knb);
        PH_MFMA(1, aB0, aB1, aB2, aB3, b10, b11, b12, b13);
        asm volatile("s_waitcnt vmcnt(4)" ::: "memory");  // land A(t+1) loads 2,3; B(t+2) flying
        asm volatile("s_barrier" ::: "memory");
    }

    asm volatile("s_waitcnt vmcnt(0)" ::: "memory");  // drain dead tail stages

    // C/D layout (m89): col = lane&15, row = (lane>>4)*4 + j
    const int crow = bm + wr * 128 + kq4 * 4;
    const int ccol = bn + wc * 64 + fr;
#pragma unroll
    for (int m = 0; m < 8; ++m)
#pragma unroll
        for (int n = 0; n < 4; ++n)
#pragma unroll
            for (int j = 0; j < 4; ++j)
                C[(size_t)(crow + m * 16 + j) * N_DIM + ccol + n * 16] = acc[m][n][j];
}

// ---------------------------------------------------------------------------
// fp32 fallback (only if ws too small)
// ---------------------------------------------------------------------------
__global__ void gemm_f32_fallback(const float* __restrict__ A,
                                  const float* __restrict__ B,
                                  float* __restrict__ C,
                                  const float* __restrict__ thrp) {
    __shared__ float As[32][33];
    __shared__ float Bs[32][33];
    const float thr = thrp[0];
    const int tx = threadIdx.x, ty = threadIdx.y;
    const int row = blockIdx.y * 32 + ty;
    float acc = 0.0f;
    for (int k0 = 0; k0 < K_DIM; k0 += 32) {
        float a = A[(size_t)row * K_DIM + k0 + tx];
        As[ty][tx] = (fabsf(a) > thr) ? a : 0.0f;
        Bs[ty][tx] = B[(size_t)(blockIdx.x * 32 + ty) * K_DIM + k0 + tx];
        __syncthreads();
#pragma unroll 8
        for (int kk = 0; kk < 32; ++kk)
            acc += As[ty][kk] * Bs[tx][kk];
        __syncthreads();
    }
    C[(size_t)row * N_DIM + blockIdx.x * 32 + tx] = acc;
}

// ---------------------------------------------------------------------------
extern "C" void kernel_launch(void* const* d_in, const int* in_sizes, int n_in,
                              void* d_out, int out_size, void* d_ws, size_t ws_size,
                              hipStream_t stream) {
    const float* x    = (const float*)d_in[0];
    const float* w    = (const float*)d_in[1];
    const float* thrp = (const float*)d_in[2];
    float* out = (float*)d_out;

    const size_t elems = (size_t)M_DIM * K_DIM;
    if (ws_size >= 2 * elems * sizeof(unsigned short)) {
        unsigned short* Ab = (unsigned short*)d_ws;
        unsigned short* Bb = Ab + elems;
        const int n8 = (int)(elems / 8);
        prune_cvt2<<<2048, 256, 0, stream>>>(x, w, Ab, Bb, thrp, n8);
        gemm_8phase<<<dim3(256), dim3(512), 0, stream>>>(Ab, Bb, out);
    } else {
        dim3 grid(N_DIM / 32, M_DIM / 32), blk(32, 32);
        gemm_f32_fallback<<<grid, blk, 0, stream>>>(x, w, out, thrp);
    }
}